// Round 3
// baseline (213.783 us; speedup 1.0000x reference)
//
#include <hip/hip_runtime.h>
#include <hip/hip_bf16.h>
#include <cstdint>

typedef __bf16 bf16_t;
typedef __bf16 bf16x8 __attribute__((ext_vector_type(8)));
typedef float f32x4 __attribute__((ext_vector_type(4)));

__device__ __forceinline__ void g2lds16(const bf16_t* g, bf16_t* l) {
  __builtin_amdgcn_global_load_lds(
      (const __attribute__((address_space(1))) uint32_t*)g,
      (__attribute__((address_space(3))) uint32_t*)l, 16, 0, 0);
}

// f32 -> bf16 cast, 8 elements/thread
__global__ __launch_bounds__(256) void cast_f32_bf16(const float* __restrict__ src,
                                                     bf16_t* __restrict__ dst, int n8) {
  int i = blockIdx.x * 256 + threadIdx.x;
  if (i >= n8) return;
  const float4* s4 = reinterpret_cast<const float4*>(src);
  float4 a = s4[2 * i], b = s4[2 * i + 1];
  bf16x8 o;
  o[0] = (bf16_t)a.x; o[1] = (bf16_t)a.y; o[2] = (bf16_t)a.z; o[3] = (bf16_t)a.w;
  o[4] = (bf16_t)b.x; o[5] = (bf16_t)b.y; o[6] = (bf16_t)b.z; o[7] = (bf16_t)b.w;
  reinterpret_cast<bf16x8*>(dst)[i] = o;
}

// Row softmax over 2048 bf16 elements, in place. One block (256 thr) per row.
__global__ __launch_bounds__(256) void softmax_rows(bf16_t* __restrict__ P) {
  const int t = threadIdx.x, lane = t & 63, wave = t >> 6;
  bf16_t* p = P + (long)blockIdx.x * 2048;
  bf16x8 v = reinterpret_cast<bf16x8*>(p)[t];
  float f[8];
  #pragma unroll
  for (int e = 0; e < 8; e++) f[e] = (float)v[e];
  float m = f[0];
  #pragma unroll
  for (int e = 1; e < 8; e++) m = fmaxf(m, f[e]);
  #pragma unroll
  for (int o = 32; o > 0; o >>= 1) m = fmaxf(m, __shfl_xor(m, o));
  __shared__ float red[4];
  if (lane == 0) red[wave] = m;
  __syncthreads();
  m = fmaxf(fmaxf(red[0], red[1]), fmaxf(red[2], red[3]));
  float s = 0.f;
  #pragma unroll
  for (int e = 0; e < 8; e++) { f[e] = __expf(f[e] - m); s += f[e]; }
  #pragma unroll
  for (int o = 32; o > 0; o >>= 1) s += __shfl_xor(s, o);
  __syncthreads();
  if (lane == 0) red[wave] = s;
  __syncthreads();
  s = red[0] + red[1] + red[2] + red[3];
  const float inv = 1.0f / s;
  #pragma unroll
  for (int e = 0; e < 8; e++) v[e] = (bf16_t)(f[e] * inv);
  reinterpret_cast<bf16x8*>(p)[t] = v;
}

// ---------------------------------------------------------------------------
// 256x256 8-phase BT-GEMM (BK=64, 512 threads = 8 waves as 2x4).
// C[m,n] = sum_k A[m,k]*B[n,k]. Per-wave output: rows {mh*128+wr*64+0..63} x
// cols {nh*128+wc*32+0..31} so quadrant (mh,nh) reads only stage-half mh of A
// and nh of B. Stage schedule depth-6 (3 half-tile-pairs in flight), counted
// vmcnt(6) at phases 3 and 7 only (never 0 in the loop).
// XCD-aware bijective block swizzle (total blocks % 8 == 0 for all launches).
// LDS swizzle: byte ^= ((row&7)<<4), applied on pre-swizzled global source
// (linear LDS dest for global_load_lds) and on ds_read addresses.
// MODE 0: QKV epilogue (bias; Q,K row-major bf16; V transposed to Vt)
// MODE 1: bf16 out, scaled (scores);  MODE 2: f32 out (PV)
// ---------------------------------------------------------------------------
template<int MODE>
__global__ __launch_bounds__(512, 2) void gemm8p(
    const bf16_t* __restrict__ A, const bf16_t* __restrict__ B,
    int lda, int ldb, int K, int ldo,
    long sAz, long sBz, long sOz,
    bf16_t* __restrict__ o_q, bf16_t* __restrict__ o_k, bf16_t* __restrict__ o_vt,
    const float* __restrict__ bqp, const float* __restrict__ bkp, const float* __restrict__ bvp,
    bf16_t* __restrict__ o_s, float scale, float* __restrict__ o_f)
{
  __shared__ bf16_t As[2][16384];   // [buf][256 rows x 64 cols]
  __shared__ bf16_t Bs[2][16384];
  const int t = threadIdx.x;
  const int lane = t & 63;
  const int wave = t >> 6;
  const int wr = wave >> 2, wc = wave & 3;

  // XCD-aware bijective swizzle of the global linear block id (total % 8 == 0)
  const int gx = gridDim.x;
  const unsigned gxy = (unsigned)gx * gridDim.y;
  const unsigned orig = (blockIdx.z * gridDim.y + blockIdx.y) * (unsigned)gx + blockIdx.x;
  const unsigned total = gxy * gridDim.z;
  const unsigned cpx = total >> 3;
  const unsigned swz = (orig & 7u) * cpx + (orig >> 3);
  const int bz = swz / gxy;
  const unsigned rem = swz - bz * gxy;
  const int by = rem / gx;
  const int bx = rem - by * gx;
  const int m0 = by * 256, n0 = bx * 256;

  A += (long)bz * sAz;
  B += (long)bz * sBz;

  // staging constants: thread t writes LDS bytes [region + t*16, +16)
  // pre-swizzled source col so that LDS[o] = G[swz(o)], swz(b)=b^(((b>>7)&7)<<4)
  const int srow = t >> 3;                                    // 0..63
  const int scolB = (((t & 7) << 4) ^ ((srow & 7) << 4));     // byte col 0..127
  const bf16_t* Abase = A + (long)m0 * lda + (scolB >> 1);
  const bf16_t* Bbase = B + (long)n0 * ldb + (scolB >> 1);

  // fragment-read constants
  const int laneRow = lane & 15;
  const int laneK16 = (lane >> 4) << 4;     // byte offset of this lane's 8-elem k-group
  const int rflip = (laneRow & 7) << 4;
  const char* AsB = (const char*)&As[0][0];
  const char* BsB = (const char*)&Bs[0][0];

  f32x4 acc[8][4];
  #pragma unroll
  for (int i = 0; i < 8; ++i)
    #pragma unroll
    for (int j = 0; j < 4; ++j) { f32x4 z = {0.f, 0.f, 0.f, 0.f}; acc[i][j] = z; }

#define STAGE_A(bb, h, kt) do { \
    const bf16_t* _s = Abase + (long)((h) * 128 + srow) * lda + (kt) * 64; \
    g2lds16(_s, &As[bb][(h) * 8192 + t * 8]); \
    g2lds16(_s + (long)64 * lda, &As[bb][(h) * 8192 + 4096 + t * 8]); \
  } while (0)
#define STAGE_B(bb, h, kt) do { \
    const bf16_t* _s = Bbase + (long)((h) * 128 + srow) * ldb + (kt) * 64; \
    g2lds16(_s, &Bs[bb][(h) * 8192 + t * 8]); \
    g2lds16(_s + (long)64 * ldb, &Bs[bb][(h) * 8192 + 4096 + t * 8]); \
  } while (0)

  bf16x8 a[4][2], b[2][2];

#define LOADA(mh, bc) do { \
    _Pragma("unroll") \
    for (int fi2 = 0; fi2 < 4; ++fi2) { \
      const int row = (mh) * 128 + wr * 64 + fi2 * 16 + laneRow; \
      _Pragma("unroll") \
      for (int ks = 0; ks < 2; ++ks) { \
        const int off = ((bc) * 32768 + (row << 7) + (ks << 6) + laneK16) ^ rflip; \
        a[fi2][ks] = *reinterpret_cast<const bf16x8*>(AsB + off); \
      } \
    } \
  } while (0)
#define LOADB(nh, bc) do { \
    _Pragma("unroll") \
    for (int fj2 = 0; fj2 < 2; ++fj2) { \
      const int row = (nh) * 128 + wc * 32 + fj2 * 16 + laneRow; \
      _Pragma("unroll") \
      for (int ks = 0; ks < 2; ++ks) { \
        const int off = ((bc) * 32768 + (row << 7) + (ks << 6) + laneK16) ^ rflip; \
        b[fj2][ks] = *reinterpret_cast<const bf16x8*>(BsB + off); \
      } \
    } \
  } while (0)
#define QUAD(mh, nh) do { \
    _Pragma("unroll") \
    for (int fi2 = 0; fi2 < 4; ++fi2) \
      _Pragma("unroll") \
      for (int ks = 0; ks < 2; ++ks) \
        _Pragma("unroll") \
        for (int fj2 = 0; fj2 < 2; ++fj2) \
          acc[(mh) * 4 + fi2][(nh) * 2 + fj2] = __builtin_amdgcn_mfma_f32_16x16x32_bf16( \
              a[fi2][ks], b[fj2][ks], acc[(mh) * 4 + fi2][(nh) * 2 + fj2], 0, 0, 0); \
  } while (0)
#define PH_MID() do { \
    __builtin_amdgcn_s_barrier(); \
    asm volatile("s_waitcnt lgkmcnt(0)" ::: "memory"); \
    __builtin_amdgcn_sched_barrier(0); \
    __builtin_amdgcn_s_setprio(1); \
  } while (0)
#define PH_END() do { \
    __builtin_amdgcn_s_setprio(0); \
    __builtin_amdgcn_s_barrier(); \
  } while (0)
#define PH_ENDV() do { \
    __builtin_amdgcn_s_setprio(0); \
    asm volatile("s_waitcnt vmcnt(6)" ::: "memory"); \
    __builtin_amdgcn_s_barrier(); \
  } while (0)

  const int NT = K >> 6;
  const int NITER = K >> 7;

  // prologue: T0 fully + T1.A0, T1.B0, T1.A1  (14 loads); retire T0 (first 8)
  STAGE_A(0, 0, 0);
  STAGE_B(0, 0, 0);
  STAGE_A(0, 1, 0);
  STAGE_B(0, 1, 0);
  STAGE_A(1, 0, 1);
  STAGE_B(1, 0, 1);
  STAGE_A(1, 1, 1);
  asm volatile("s_waitcnt vmcnt(6)" ::: "memory");
  __builtin_amdgcn_s_barrier();

  for (int it = 0; it < NITER; ++it) {
    const int T1 = 2 * it + 1;
    int T2 = 2 * it + 2; if (T2 >= NT) T2 = NT - 1;   // clamped prefetch (garbage,
    int T3 = 2 * it + 3; if (T3 >= NT) T3 = NT - 1;   // never computed) keeps vmcnt exact
    // p0: quad(0,0) from buf0; stage T1.B1 (buf1.B.h1 last read prev p7)
    LOADA(0, 0); LOADB(0, 0);
    STAGE_B(1, 1, T1);
    PH_MID(); QUAD(0, 0); PH_END();
    // p1: quad(0,1); stage T2.A0 (buf0.A.h0 last read p0)
    LOADB(1, 0);
    STAGE_A(0, 0, T2);
    PH_MID(); QUAD(0, 1); PH_END();
    // p2: quad(1,0); no stage
    LOADA(1, 0); LOADB(0, 0);
    PH_MID(); QUAD(1, 0); PH_END();
    // p3: quad(1,1); stage T2.B0 + T2.A1 (last reads p2); counted wait -> T1 done
    LOADB(1, 0);
    STAGE_B(0, 0, T2);
    STAGE_A(0, 1, T2);
    PH_MID(); QUAD(1, 1); PH_ENDV();
    // p4: quad(0,0) from buf1; stage T2.B1 (buf0.B.h1 last read p3)
    LOADA(0, 1); LOADB(0, 1);
    STAGE_B(0, 1, T2);
    PH_MID(); QUAD(0, 0); PH_END();
    // p5: quad(0,1); stage T3.A0 (buf1.A.h0 last read p4)
    LOADB(1, 1);
    STAGE_A(1, 0, T3);
    PH_MID(); QUAD(0, 1); PH_END();
    // p6: quad(1,0); no stage
    LOADA(1, 1); LOADB(0, 1);
    PH_MID(); QUAD(1, 0); PH_END();
    // p7: quad(1,1); stage T3.B0 + T3.A1 (last reads p6); counted wait -> T2 done
    LOADB(1, 1);
    STAGE_B(1, 0, T3);
    STAGE_A(1, 1, T3);
    PH_MID(); QUAD(1, 1); PH_ENDV();
  }

  // epilogue: C/D frag layout col=lane&15, row=(lane>>4)*4+r
  const int er = (lane >> 4) << 2;
  const int ec = lane & 15;
  #pragma unroll
  for (int mh = 0; mh < 2; ++mh)
  #pragma unroll
  for (int fi2 = 0; fi2 < 4; ++fi2) {
    const int mg = m0 + mh * 128 + wr * 64 + fi2 * 16 + er;
    #pragma unroll
    for (int nh = 0; nh < 2; ++nh)
    #pragma unroll
    for (int fj2 = 0; fj2 < 2; ++fj2) {
      const int ng = n0 + nh * 128 + wc * 32 + fj2 * 16 + ec;
      const f32x4 v = acc[mh * 4 + fi2][nh * 2 + fj2];
      if constexpr (MODE == 0) {
        if (ng < 1024) {
          const float bb = bqp[ng];
          #pragma unroll
          for (int r = 0; r < 4; ++r)
            o_q[(long)(mg + r) * 1024 + ng] = (bf16_t)(v[r] + bb);
        } else if (ng < 2048) {
          const int nn = ng - 1024;
          const float bb = bkp[nn];
          #pragma unroll
          for (int r = 0; r < 4; ++r)
            o_k[(long)(mg + r) * 1024 + nn] = (bf16_t)(v[r] + bb);
        } else {
          const int nn = ng - 2048;
          const float bb = bvp[nn];
          const int bat = mg >> 11, sr = mg & 2047;
          union { bf16_t h[4]; uint2 u; } pk;
          #pragma unroll
          for (int r = 0; r < 4; ++r) pk.h[r] = (bf16_t)(v[r] + bb);
          *reinterpret_cast<uint2*>(&o_vt[((long)bat * 1024 + nn) * 2048 + sr]) = pk.u;
        }
      } else if constexpr (MODE == 1) {
        bf16_t* os = o_s + (long)bz * sOz;
        #pragma unroll
        for (int r = 0; r < 4; ++r)
          os[(long)(mg + r) * ldo + ng] = (bf16_t)(v[r] * scale);
      } else {
        float* of = o_f + (long)bz * sOz;
        #pragma unroll
        for (int r = 0; r < 4; ++r)
          of[(long)(mg + r) * ldo + ng] = v[r];
      }
    }
  }
#undef STAGE_A
#undef STAGE_B
#undef LOADA
#undef LOADB
#undef QUAD
#undef PH_MID
#undef PH_END
#undef PH_ENDV
}

extern "C" void kernel_launch(void* const* d_in, const int* in_sizes, int n_in,
                              void* d_out, int out_size, void* d_ws, size_t ws_size,
                              hipStream_t stream) {
  const float* X  = (const float*)d_in[0];
  const float* Wq = (const float*)d_in[1];
  const float* bq = (const float*)d_in[2];
  const float* Wk = (const float*)d_in[3];
  const float* bk = (const float*)d_in[4];
  const float* Wv = (const float*)d_in[5];
  const float* bv = (const float*)d_in[6];
  float* out = (float*)d_out;

  // ws layout (80 MiB):
  // [0:16M) Q bf16 [8192,1024] | [16:32M) K bf16 | [32:48M) Vt bf16 [4,1024,2048]
  // [48:64M) Xb bf16 | [64:70M) Wc bf16 [3072,1024] | [48:80M) P bf16 [4,2048,2048]
  constexpr long SEG = 16777216;
  char* ws = (char*)d_ws;
  bf16_t* Q  = (bf16_t*)(ws + 0 * SEG);
  bf16_t* Kc = (bf16_t*)(ws + 1 * SEG);
  bf16_t* Vt = (bf16_t*)(ws + 2 * SEG);
  bf16_t* Xb = (bf16_t*)(ws + 3 * SEG);
  bf16_t* Wc = (bf16_t*)(ws + 4 * SEG);
  bf16_t* P  = (bf16_t*)(ws + 3 * SEG);

  cast_f32_bf16<<<4096, 256, 0, stream>>>(X,  Xb, 1048576);
  cast_f32_bf16<<<512,  256, 0, stream>>>(Wq, Wc,           131072);
  cast_f32_bf16<<<512,  256, 0, stream>>>(Wk, Wc + 1048576, 131072);
  cast_f32_bf16<<<512,  256, 0, stream>>>(Wv, Wc + 2097152, 131072);

  dim3 blk(512);
  {  // QKV: M=8192, N=3072, K=1024  (384 blocks)
    dim3 g(3072 / 256, 8192 / 256, 1);
    gemm8p<0><<<g, blk, 0, stream>>>(Xb, Wc, 1024, 1024, 1024, 1024, 0, 0, 0,
                                     Q, Kc, Vt, bq, bk, bv, nullptr, 0.f, nullptr);
  }
  {  // scores: per batch M=N=2048, K=1024; P = (Q K^T)/32 in bf16  (256 blocks)
    dim3 g(2048 / 256, 2048 / 256, 4);
    gemm8p<1><<<g, blk, 0, stream>>>(Q, Kc, 1024, 1024, 1024, 2048,
                                     2097152, 2097152, 4194304,
                                     nullptr, nullptr, nullptr, nullptr, nullptr, nullptr,
                                     P, 0.03125f, nullptr);
  }
  softmax_rows<<<8192, 256, 0, stream>>>(P);
  {  // PV: per batch M=2048, N=1024, K=2048 -> f32 out  (128 blocks)
    dim3 g(1024 / 256, 2048 / 256, 4);
    gemm8p<2><<<g, blk, 0, stream>>>(P, Vt, 2048, 2048, 2048, 1024,
                                     4194304, 2097152, 2097152,
                                     nullptr, nullptr, nullptr, nullptr, nullptr, nullptr,
                                     nullptr, 0.f, out);
  }
}

// Round 4
// 186.413 us; speedup vs baseline: 1.1468x; 1.1468x over previous
//
#include <hip/hip_runtime.h>
#include <hip/hip_bf16.h>
#include <cstdint>

typedef __bf16 bf16_t;
typedef __bf16 bf16x8 __attribute__((ext_vector_type(8)));
typedef float f32x4 __attribute__((ext_vector_type(4)));

__device__ __forceinline__ void g2lds16(const bf16_t* g, bf16_t* l) {
  __builtin_amdgcn_global_load_lds(
      (const __attribute__((address_space(1))) uint32_t*)g,
      (__attribute__((address_space(3))) uint32_t*)l, 16, 0, 0);
}

// f32 -> bf16 cast, 8 elements/thread
__global__ __launch_bounds__(256) void cast_f32_bf16(const float* __restrict__ src,
                                                     bf16_t* __restrict__ dst, int n8) {
  int i = blockIdx.x * 256 + threadIdx.x;
  if (i >= n8) return;
  const float4* s4 = reinterpret_cast<const float4*>(src);
  float4 a = s4[2 * i], b = s4[2 * i + 1];
  bf16x8 o;
  o[0] = (bf16_t)a.x; o[1] = (bf16_t)a.y; o[2] = (bf16_t)a.z; o[3] = (bf16_t)a.w;
  o[4] = (bf16_t)b.x; o[5] = (bf16_t)b.y; o[6] = (bf16_t)b.z; o[7] = (bf16_t)b.w;
  reinterpret_cast<bf16x8*>(dst)[i] = o;
}

// Row softmax over 2048 bf16 elements, in place. One block (256 thr) per row.
__global__ __launch_bounds__(256) void softmax_rows(bf16_t* __restrict__ P) {
  const int t = threadIdx.x, lane = t & 63, wave = t >> 6;
  bf16_t* p = P + (long)blockIdx.x * 2048;
  bf16x8 v = reinterpret_cast<bf16x8*>(p)[t];
  float f[8];
  #pragma unroll
  for (int e = 0; e < 8; e++) f[e] = (float)v[e];
  float m = f[0];
  #pragma unroll
  for (int e = 1; e < 8; e++) m = fmaxf(m, f[e]);
  #pragma unroll
  for (int o = 32; o > 0; o >>= 1) m = fmaxf(m, __shfl_xor(m, o));
  __shared__ float red[4];
  if (lane == 0) red[wave] = m;
  __syncthreads();
  m = fmaxf(fmaxf(red[0], red[1]), fmaxf(red[2], red[3]));
  float s = 0.f;
  #pragma unroll
  for (int e = 0; e < 8; e++) { f[e] = __expf(f[e] - m); s += f[e]; }
  #pragma unroll
  for (int o = 32; o > 0; o >>= 1) s += __shfl_xor(s, o);
  __syncthreads();
  if (lane == 0) red[wave] = s;
  __syncthreads();
  s = red[0] + red[1] + red[2] + red[3];
  const float inv = 1.0f / s;
  #pragma unroll
  for (int e = 0; e < 8; e++) v[e] = (bf16_t)(f[e] * inv);
  reinterpret_cast<bf16x8*>(p)[t] = v;
}

// ---------------------------------------------------------------------------
// 256x256 8-phase BT-GEMM (BK=64, 512 threads = 8 waves as 2x4) — R2 schedule.
// MODE 0: QKV epilogue (bias; Q,K row-major bf16; V transposed to Vt)
// MODE 1: bf16 out, scaled (scores)
// ---------------------------------------------------------------------------
template<int MODE>
__global__ __launch_bounds__(512, 2) void gemm8p(
    const bf16_t* __restrict__ A, const bf16_t* __restrict__ B,
    int lda, int ldb, int K, int ldo,
    long sAz, long sBz, long sOz,
    bf16_t* __restrict__ o_q, bf16_t* __restrict__ o_k, bf16_t* __restrict__ o_vt,
    const float* __restrict__ bqp, const float* __restrict__ bkp, const float* __restrict__ bvp,
    bf16_t* __restrict__ o_s, float scale, float* __restrict__ o_f)
{
  __shared__ bf16_t As[2][16384];   // [buf][256 rows x 64 cols]
  __shared__ bf16_t Bs[2][16384];
  const int t = threadIdx.x;
  const int lane = t & 63;
  const int wave = t >> 6;
  const int wr = wave >> 2, wc = wave & 3;
  const int m0 = blockIdx.y * 256, n0 = blockIdx.x * 256;
  const int bz = blockIdx.z;
  A += (long)bz * sAz;
  B += (long)bz * sBz;

  const int srow = t >> 3;                                    // 0..63
  const int scolB = (((t & 7) << 4) ^ ((srow & 7) << 4));     // byte col 0..127
  const bf16_t* Abase = A + (long)m0 * lda + (scolB >> 1);
  const bf16_t* Bbase = B + (long)n0 * ldb + (scolB >> 1);

  const int laneRow = lane & 15;
  const int laneK16 = (lane >> 4) << 4;
  const int rflip = (laneRow & 7) << 4;
  const char* AsB = (const char*)&As[0][0];
  const char* BsB = (const char*)&Bs[0][0];

  f32x4 acc[8][4];
  #pragma unroll
  for (int i = 0; i < 8; ++i)
    #pragma unroll
    for (int j = 0; j < 4; ++j) { f32x4 z = {0.f, 0.f, 0.f, 0.f}; acc[i][j] = z; }

#define STAGE_A(bb, h, kt) do { \
    const bf16_t* _s = Abase + (long)((h) * 128 + srow) * lda + (kt) * 64; \
    g2lds16(_s, &As[bb][(h) * 8192 + t * 8]); \
    g2lds16(_s + (long)64 * lda, &As[bb][(h) * 8192 + 4096 + t * 8]); \
  } while (0)
#define STAGE_B(bb, h, kt) do { \
    const bf16_t* _s = Bbase + (long)((h) * 128 + srow) * ldb + (kt) * 64; \
    g2lds16(_s, &Bs[bb][(h) * 8192 + t * 8]); \
    g2lds16(_s + (long)64 * ldb, &Bs[bb][(h) * 8192 + 4096 + t * 8]); \
  } while (0)

  bf16x8 a[4][2], b[2][2];

#define LOADA(mh, bc) do { \
    _Pragma("unroll") \
    for (int fi2 = 0; fi2 < 4; ++fi2) { \
      const int row = (mh) * 128 + wr * 64 + fi2 * 16 + laneRow; \
      _Pragma("unroll") \
      for (int ks = 0; ks < 2; ++ks) { \
        const int off = ((bc) * 32768 + (row << 7) + (ks << 6) + laneK16) ^ rflip; \
        a[fi2][ks] = *reinterpret_cast<const bf16x8*>(AsB + off); \
      } \
    } \
  } while (0)
#define LOADB(nh, bc) do { \
    _Pragma("unroll") \
    for (int fj2 = 0; fj2 < 2; ++fj2) { \
      const int row = (nh) * 128 + wc * 32 + fj2 * 16 + laneRow; \
      _Pragma("unroll") \
      for (int ks = 0; ks < 2; ++ks) { \
        const int off = ((bc) * 32768 + (row << 7) + (ks << 6) + laneK16) ^ rflip; \
        b[fj2][ks] = *reinterpret_cast<const bf16x8*>(BsB + off); \
      } \
    } \
  } while (0)
#define QUAD(mh, nh) do { \
    _Pragma("unroll") \
    for (int fi2 = 0; fi2 < 4; ++fi2) \
      _Pragma("unroll") \
      for (int ks = 0; ks < 2; ++ks) \
        _Pragma("unroll") \
        for (int fj2 = 0; fj2 < 2; ++fj2) \
          acc[(mh) * 4 + fi2][(nh) * 2 + fj2] = __builtin_amdgcn_mfma_f32_16x16x32_bf16( \
              a[fi2][ks], b[fj2][ks], acc[(mh) * 4 + fi2][(nh) * 2 + fj2], 0, 0, 0); \
  } while (0)
#define PH_MID() do { \
    __builtin_amdgcn_s_barrier(); \
    asm volatile("s_waitcnt lgkmcnt(0)" ::: "memory"); \
    __builtin_amdgcn_sched_barrier(0); \
    __builtin_amdgcn_s_setprio(1); \
  } while (0)
#define PH_END() do { \
    __builtin_amdgcn_s_setprio(0); \
    __builtin_amdgcn_s_barrier(); \
  } while (0)
#define PH_ENDV() do { \
    __builtin_amdgcn_s_setprio(0); \
    asm volatile("s_waitcnt vmcnt(4)" ::: "memory"); \
    __builtin_amdgcn_s_barrier(); \
  } while (0)

  const int NT = K >> 6;
  const int NITER = K >> 7;

  // prologue: tile0 (buf0) fully + tile1 (buf1) halves 0
  STAGE_A(0, 0, 0);
  STAGE_B(0, 0, 0);
  STAGE_A(0, 1, 0);
  STAGE_B(0, 1, 0);
  STAGE_A(1, 0, 1);
  STAGE_B(1, 0, 1);
  asm volatile("s_waitcnt vmcnt(4)" ::: "memory");
  __builtin_amdgcn_s_barrier();

  for (int it = 0; it < NITER; ++it) {
    const int T1 = 2 * it + 1;
    int T2 = 2 * it + 2; if (T2 >= NT) T2 = NT - 1;   // clamped prefetch (garbage,
    int T3 = 2 * it + 3; if (T3 >= NT) T3 = NT - 1;   // never computed) keeps vmcnt exact
    // p0: quad(0,0) from buf0; stage T1.A1
    LOADA(0, 0); LOADB(0, 0);
    STAGE_A(1, 1, T1);
    PH_MID(); QUAD(0, 0); PH_END();
    // p1: quad(0,1); stage T1.B1
    LOADB(1, 0);
    STAGE_B(1, 1, T1);
    PH_MID(); QUAD(0, 1); PH_END();
    // p2: quad(1,0); stage T2.A0
    LOADA(1, 0); LOADB(0, 0);
    STAGE_A(0, 0, T2);
    PH_MID(); QUAD(1, 0); PH_END();
    // p3: quad(1,1); stage T2.B0; counted wait for T1
    LOADB(1, 0);
    STAGE_B(0, 0, T2);
    PH_MID(); QUAD(1, 1); PH_ENDV();
    // p4: quad(0,0) from buf1; stage T2.A1
    LOADA(0, 1); LOADB(0, 1);
    STAGE_A(0, 1, T2);
    PH_MID(); QUAD(0, 0); PH_END();
    // p5: quad(0,1); stage T2.B1
    LOADB(1, 1);
    STAGE_B(0, 1, T2);
    PH_MID(); QUAD(0, 1); PH_END();
    // p6: quad(1,0); stage T3.A0
    LOADA(1, 1); LOADB(0, 1);
    STAGE_A(1, 0, T3);
    PH_MID(); QUAD(1, 0); PH_END();
    // p7: quad(1,1); stage T3.B0; counted wait for T2
    LOADB(1, 1);
    STAGE_B(1, 0, T3);
    PH_MID(); QUAD(1, 1); PH_ENDV();
  }

  // epilogue: C/D frag layout col=lane&15, row=(lane>>4)*4+r
  const int er = (lane >> 4) << 2;
  const int ec = lane & 15;
  #pragma unroll
  for (int mh = 0; mh < 2; ++mh)
  #pragma unroll
  for (int fi2 = 0; fi2 < 4; ++fi2) {
    const int mg = m0 + mh * 128 + wr * 64 + fi2 * 16 + er;
    #pragma unroll
    for (int nh = 0; nh < 2; ++nh)
    #pragma unroll
    for (int fj2 = 0; fj2 < 2; ++fj2) {
      const int ng = n0 + nh * 128 + wc * 32 + fj2 * 16 + ec;
      const f32x4 v = acc[mh * 4 + fi2][nh * 2 + fj2];
      if constexpr (MODE == 0) {
        if (ng < 1024) {
          const float bb = bqp[ng];
          #pragma unroll
          for (int r = 0; r < 4; ++r)
            o_q[(long)(mg + r) * 1024 + ng] = (bf16_t)(v[r] + bb);
        } else if (ng < 2048) {
          const int nn = ng - 1024;
          const float bb = bkp[nn];
          #pragma unroll
          for (int r = 0; r < 4; ++r)
            o_k[(long)(mg + r) * 1024 + nn] = (bf16_t)(v[r] + bb);
        } else {
          const int nn = ng - 2048;
          const float bb = bvp[nn];
          const int bat = mg >> 11, sr = mg & 2047;
          union { bf16_t h[4]; uint2 u; } pk;
          #pragma unroll
          for (int r = 0; r < 4; ++r) pk.h[r] = (bf16_t)(v[r] + bb);
          *reinterpret_cast<uint2*>(&o_vt[((long)bat * 1024 + nn) * 2048 + sr]) = pk.u;
        }
      } else {
        bf16_t* os = o_s + (long)bz * sOz;
        #pragma unroll
        for (int r = 0; r < 4; ++r)
          os[(long)(mg + r) * ldo + ng] = (bf16_t)(v[r] * scale);
      }
    }
  }
#undef STAGE_A
#undef STAGE_B
#undef LOADA
#undef LOADB
#undef QUAD
#undef PH_MID
#undef PH_END
#undef PH_ENDV
}

// ---------------------------------------------------------------------------
// PV GEMM: 128(M)x256(N) tile, BK=64, 3 LDS buffers (144 KiB), 2 phases/tile.
// Grid (1024/256, 2048/128, 4) = 256 blocks -> full machine (vs 128 at 256^2).
// Stage tile T+2 during tile T (slot (T+2)%3 = slot of tile T-1, whose last
// read finished one barrier earlier). vmcnt(6) once per tile retires exactly
// tile T+1's 6 loads (queue: 6 + 4 + 2 = 12 -> 6).
// ---------------------------------------------------------------------------
__global__ __launch_bounds__(512, 2) void gemm128pv(
    const bf16_t* __restrict__ A, const bf16_t* __restrict__ B,
    int lda, int ldb, int K, int ldo,
    long sAz, long sBz, long sOz, float* __restrict__ o_f)
{
  __shared__ bf16_t As3[3][8192];    // [buf][128 rows x 64 cols]
  __shared__ bf16_t Bs3[3][16384];   // [buf][256 rows x 64 cols]
  const int t = threadIdx.x;
  const int lane = t & 63;
  const int wave = t >> 6;
  const int wr = wave >> 2, wc = wave & 3;
  const int m0 = blockIdx.y * 128, n0 = blockIdx.x * 256;
  const int bz = blockIdx.z;
  A += (long)bz * sAz;
  B += (long)bz * sBz;

  const int srow = t >> 3;                                    // 0..63
  const int scolB = (((t & 7) << 4) ^ ((srow & 7) << 4));     // byte col 0..127
  const bf16_t* Abase = A + (long)m0 * lda + (scolB >> 1);
  const bf16_t* Bbase = B + (long)n0 * ldb + (scolB >> 1);

  const int laneRow = lane & 15;
  const int laneK16 = (lane >> 4) << 4;
  const int rflip = (laneRow & 7) << 4;
  const char* AsB = (const char*)&As3[0][0];
  const char* BsB = (const char*)&Bs3[0][0];

  f32x4 acc[4][4];
  #pragma unroll
  for (int i = 0; i < 4; ++i)
    #pragma unroll
    for (int j = 0; j < 4; ++j) { f32x4 z = {0.f, 0.f, 0.f, 0.f}; acc[i][j] = z; }

#define PSTAGE_A(se, kt) do { \
    const bf16_t* _s = Abase + (long)srow * lda + (kt) * 64; \
    g2lds16(_s, &As3[0][0] + (se) + t * 8); \
    g2lds16(_s + (long)64 * lda, &As3[0][0] + (se) + 4096 + t * 8); \
  } while (0)
#define PSTAGE_B(se, h, kt) do { \
    const bf16_t* _s = Bbase + (long)((h) * 128 + srow) * ldb + (kt) * 64; \
    g2lds16(_s, &Bs3[0][0] + (se) + (h) * 8192 + t * 8); \
    g2lds16(_s + (long)64 * ldb, &Bs3[0][0] + (se) + (h) * 8192 + 4096 + t * 8); \
  } while (0)

  bf16x8 a[4][2], b[2][2];

#define PLOADA(cAb) do { \
    _Pragma("unroll") \
    for (int fi2 = 0; fi2 < 4; ++fi2) { \
      const int row = wr * 64 + fi2 * 16 + laneRow; \
      _Pragma("unroll") \
      for (int ks = 0; ks < 2; ++ks) { \
        const int off = (cAb) + (((row << 7) + (ks << 6) + laneK16) ^ rflip); \
        a[fi2][ks] = *reinterpret_cast<const bf16x8*>(AsB + off); \
      } \
    } \
  } while (0)
#define PLOADB(nh, cBb) do { \
    _Pragma("unroll") \
    for (int fj2 = 0; fj2 < 2; ++fj2) { \
      const int row = (nh) * 128 + wc * 32 + fj2 * 16 + laneRow; \
      _Pragma("unroll") \
      for (int ks = 0; ks < 2; ++ks) { \
        const int off = (cBb) + (((row << 7) + (ks << 6) + laneK16) ^ rflip); \
        b[fj2][ks] = *reinterpret_cast<const bf16x8*>(BsB + off); \
      } \
    } \
  } while (0)
#define PQUAD(nh) do { \
    _Pragma("unroll") \
    for (int fi2 = 0; fi2 < 4; ++fi2) \
      _Pragma("unroll") \
      for (int ks = 0; ks < 2; ++ks) \
        _Pragma("unroll") \
        for (int fj2 = 0; fj2 < 2; ++fj2) \
          acc[fi2][(nh) * 2 + fj2] = __builtin_amdgcn_mfma_f32_16x16x32_bf16( \
              a[fi2][ks], b[fj2][ks], acc[fi2][(nh) * 2 + fj2], 0, 0, 0); \
  } while (0)
#define PPH_MID() do { \
    __builtin_amdgcn_s_barrier(); \
    asm volatile("s_waitcnt lgkmcnt(0)" ::: "memory"); \
    __builtin_amdgcn_sched_barrier(0); \
    __builtin_amdgcn_s_setprio(1); \
  } while (0)

  const int NT = K >> 6;

  // prologue: T0 -> slot0, T1 -> slot1 (12 loads); retire T0 (first 6)
  PSTAGE_A(0, 0);      PSTAGE_B(0, 0, 0);      PSTAGE_B(0, 1, 0);
  PSTAGE_A(8192, 1);   PSTAGE_B(16384, 0, 1);  PSTAGE_B(16384, 1, 1);
  asm volatile("s_waitcnt vmcnt(6)" ::: "memory");
  __builtin_amdgcn_s_barrier();

  int cAb = 0, cBb = 0;              // current buf byte offsets (A:16KB, B:32KB strides)
  int sAe = 16384, sBe = 32768;      // stage slot element offsets (slot (T+2)%3, T=0 -> slot2)

  for (int T = 0; T < NT; ++T) {
    int Tp2 = T + 2; if (Tp2 >= NT) Tp2 = NT - 1;   // clamped tail keeps vmcnt exact
    // p0: nh=0; stage T+2.A + T+2.B0
    PLOADA(cAb); PLOADB(0, cBb);
    PSTAGE_A(sAe, Tp2);
    PSTAGE_B(sBe, 0, Tp2);
    PPH_MID(); PQUAD(0);
    __builtin_amdgcn_s_setprio(0);
    __builtin_amdgcn_s_barrier();
    // p1: nh=1; stage T+2.B1; counted wait -> T+1 fully landed
    PLOADB(1, cBb);
    PSTAGE_B(sBe, 1, Tp2);
    PPH_MID(); PQUAD(1);
    __builtin_amdgcn_s_setprio(0);
    asm volatile("s_waitcnt vmcnt(6)" ::: "memory");
    __builtin_amdgcn_s_barrier();
    // rotate buffers
    cAb = (cAb == 32768) ? 0 : cAb + 16384;
    cBb = (cBb == 65536) ? 0 : cBb + 32768;
    sAe = (sAe == 16384) ? 0 : sAe + 8192;
    sBe = (sBe == 32768) ? 0 : sBe + 16384;
  }

  // epilogue: f32 out
  const int er = (lane >> 4) << 2;
  const int ec = lane & 15;
  float* of = o_f + (long)bz * sOz;
  #pragma unroll
  for (int fi2 = 0; fi2 < 4; ++fi2) {
    const int mg = m0 + wr * 64 + fi2 * 16 + er;
    #pragma unroll
    for (int nh = 0; nh < 2; ++nh)
    #pragma unroll
    for (int fj2 = 0; fj2 < 2; ++fj2) {
      const int ng = n0 + nh * 128 + wc * 32 + fj2 * 16 + ec;
      const f32x4 v = acc[fi2][nh * 2 + fj2];
      #pragma unroll
      for (int r = 0; r < 4; ++r)
        of[(long)(mg + r) * ldo + ng] = v[r];
    }
  }
#undef PSTAGE_A
#undef PSTAGE_B
#undef PLOADA
#undef PLOADB
#undef PQUAD
#undef PPH_MID
}

extern "C" void kernel_launch(void* const* d_in, const int* in_sizes, int n_in,
                              void* d_out, int out_size, void* d_ws, size_t ws_size,
                              hipStream_t stream) {
  const float* X  = (const float*)d_in[0];
  const float* Wq = (const float*)d_in[1];
  const float* bq = (const float*)d_in[2];
  const float* Wk = (const float*)d_in[3];
  const float* bk = (const float*)d_in[4];
  const float* Wv = (const float*)d_in[5];
  const float* bv = (const float*)d_in[6];
  float* out = (float*)d_out;

  // ws layout (80 MiB):
  // [0:16M) Q bf16 [8192,1024] | [16:32M) K bf16 | [32:48M) Vt bf16 [4,1024,2048]
  // [48:64M) Xb bf16 | [64:70M) Wc bf16 [3072,1024] | [48:80M) P bf16 [4,2048,2048]
  constexpr long SEG = 16777216;
  char* ws = (char*)d_ws;
  bf16_t* Q  = (bf16_t*)(ws + 0 * SEG);
  bf16_t* Kc = (bf16_t*)(ws + 1 * SEG);
  bf16_t* Vt = (bf16_t*)(ws + 2 * SEG);
  bf16_t* Xb = (bf16_t*)(ws + 3 * SEG);
  bf16_t* Wc = (bf16_t*)(ws + 4 * SEG);
  bf16_t* P  = (bf16_t*)(ws + 3 * SEG);

  cast_f32_bf16<<<4096, 256, 0, stream>>>(X,  Xb, 1048576);
  cast_f32_bf16<<<512,  256, 0, stream>>>(Wq, Wc,           131072);
  cast_f32_bf16<<<512,  256, 0, stream>>>(Wk, Wc + 1048576, 131072);
  cast_f32_bf16<<<512,  256, 0, stream>>>(Wv, Wc + 2097152, 131072);

  dim3 blk(512);
  {  // QKV: M=8192, N=3072, K=1024  (384 blocks)
    dim3 g(3072 / 256, 8192 / 256, 1);
    gemm8p<0><<<g, blk, 0, stream>>>(Xb, Wc, 1024, 1024, 1024, 1024, 0, 0, 0,
                                     Q, Kc, Vt, bq, bk, bv, nullptr, 0.f, nullptr);
  }
  {  // scores: per batch M=N=2048, K=1024; P = (Q K^T)/32 in bf16  (256 blocks)
    dim3 g(2048 / 256, 2048 / 256, 4);
    gemm8p<1><<<g, blk, 0, stream>>>(Q, Kc, 1024, 1024, 1024, 2048,
                                     2097152, 2097152, 4194304,
                                     nullptr, nullptr, nullptr, nullptr, nullptr, nullptr,
                                     P, 0.03125f, nullptr);
  }
  softmax_rows<<<8192, 256, 0, stream>>>(P);
  {  // PV: per batch M=2048, N=1024, K=2048 -> f32 out  (256 blocks)
    dim3 g(1024 / 256, 2048 / 128, 4);
    gemm128pv<<<g, blk, 0, stream>>>(P, Vt, 2048, 2048, 2048, 1024,
                                     4194304, 2097152, 2097152, out);
  }
}

// Round 5
// 178.782 us; speedup vs baseline: 1.1958x; 1.0427x over previous
//
#include <hip/hip_runtime.h>
#include <hip/hip_bf16.h>
#include <cstdint>

typedef __bf16 bf16_t;
typedef __bf16 bf16x8 __attribute__((ext_vector_type(8)));
typedef float f32x4 __attribute__((ext_vector_type(4)));

__device__ __forceinline__ void g2lds16(const bf16_t* g, bf16_t* l) {
  __builtin_amdgcn_global_load_lds(
      (const __attribute__((address_space(1))) uint32_t*)g,
      (__attribute__((address_space(3))) uint32_t*)l, 16, 0, 0);
}

// Fused f32 -> bf16 cast for X + Wq + Wk + Wv (all pow2 sizes; branch-light map).
// Group i (8 elems): i < 2^20 -> X; else w = bits[17:18] of (i - 2^20) selects W.
__global__ __launch_bounds__(256) void cast_all(
    const float* __restrict__ X, const float* __restrict__ Wq,
    const float* __restrict__ Wk, const float* __restrict__ Wv,
    bf16_t* __restrict__ Xb, bf16_t* __restrict__ Wc) {
  const int i = blockIdx.x * 256 + threadIdx.x;
  const float* src;
  bf16_t* dst;
  long off;
  if (i < (1 << 20)) {
    src = X; dst = Xb; off = i;
  } else {
    const int j = i - (1 << 20);
    const int w = j >> 17;
    off = j & ((1 << 17) - 1);
    src = (w == 0) ? Wq : (w == 1) ? Wk : Wv;
    dst = Wc + ((long)w << 20);
  }
  const float4* s4 = reinterpret_cast<const float4*>(src);
  float4 a = s4[2 * off], b = s4[2 * off + 1];
  bf16x8 o;
  o[0] = (bf16_t)a.x; o[1] = (bf16_t)a.y; o[2] = (bf16_t)a.z; o[3] = (bf16_t)a.w;
  o[4] = (bf16_t)b.x; o[5] = (bf16_t)b.y; o[6] = (bf16_t)b.z; o[7] = (bf16_t)b.w;
  reinterpret_cast<bf16x8*>(dst)[off] = o;
}

// Row softmax over 2048 bf16 elements, in place. One block (256 thr) per row.
__global__ __launch_bounds__(256) void softmax_rows(bf16_t* __restrict__ P) {
  const int t = threadIdx.x, lane = t & 63, wave = t >> 6;
  bf16_t* p = P + (long)blockIdx.x * 2048;
  bf16x8 v = reinterpret_cast<bf16x8*>(p)[t];
  float f[8];
  #pragma unroll
  for (int e = 0; e < 8; e++) f[e] = (float)v[e];
  float m = f[0];
  #pragma unroll
  for (int e = 1; e < 8; e++) m = fmaxf(m, f[e]);
  #pragma unroll
  for (int o = 32; o > 0; o >>= 1) m = fmaxf(m, __shfl_xor(m, o));
  __shared__ float red[4];
  if (lane == 0) red[wave] = m;
  __syncthreads();
  m = fmaxf(fmaxf(red[0], red[1]), fmaxf(red[2], red[3]));
  float s = 0.f;
  #pragma unroll
  for (int e = 0; e < 8; e++) { f[e] = __expf(f[e] - m); s += f[e]; }
  #pragma unroll
  for (int o = 32; o > 0; o >>= 1) s += __shfl_xor(s, o);
  __syncthreads();
  if (lane == 0) red[wave] = s;
  __syncthreads();
  s = red[0] + red[1] + red[2] + red[3];
  const float inv = 1.0f / s;
  #pragma unroll
  for (int e = 0; e < 8; e++) v[e] = (bf16_t)(f[e] * inv);
  reinterpret_cast<bf16x8*>(p)[t] = v;
}

// ---------------------------------------------------------------------------
// 256x256 8-phase BT-GEMM (BK=64, 512 threads = 8 waves as 2x4) — R2 schedule.
// Used for scores only (MODE 1): bf16 out, scaled.
// ---------------------------------------------------------------------------
template<int MODE>
__global__ __launch_bounds__(512, 2) void gemm8p(
    const bf16_t* __restrict__ A, const bf16_t* __restrict__ B,
    int lda, int ldb, int K, int ldo,
    long sAz, long sBz, long sOz,
    bf16_t* __restrict__ o_s, float scale)
{
  __shared__ bf16_t As[2][16384];   // [buf][256 rows x 64 cols]
  __shared__ bf16_t Bs[2][16384];
  const int t = threadIdx.x;
  const int lane = t & 63;
  const int wave = t >> 6;
  const int wr = wave >> 2, wc = wave & 3;
  const int m0 = blockIdx.y * 256, n0 = blockIdx.x * 256;
  const int bz = blockIdx.z;
  A += (long)bz * sAz;
  B += (long)bz * sBz;

  const int srow = t >> 3;                                    // 0..63
  const int scolB = (((t & 7) << 4) ^ ((srow & 7) << 4));     // byte col 0..127
  const bf16_t* Abase = A + (long)m0 * lda + (scolB >> 1);
  const bf16_t* Bbase = B + (long)n0 * ldb + (scolB >> 1);

  const int laneRow = lane & 15;
  const int laneK16 = (lane >> 4) << 4;
  const int rflip = (laneRow & 7) << 4;
  const char* AsB = (const char*)&As[0][0];
  const char* BsB = (const char*)&Bs[0][0];

  f32x4 acc[8][4];
  #pragma unroll
  for (int i = 0; i < 8; ++i)
    #pragma unroll
    for (int j = 0; j < 4; ++j) { f32x4 z = {0.f, 0.f, 0.f, 0.f}; acc[i][j] = z; }

#define STAGE_A(bb, h, kt) do { \
    const bf16_t* _s = Abase + (long)((h) * 128 + srow) * lda + (kt) * 64; \
    g2lds16(_s, &As[bb][(h) * 8192 + t * 8]); \
    g2lds16(_s + (long)64 * lda, &As[bb][(h) * 8192 + 4096 + t * 8]); \
  } while (0)
#define STAGE_B(bb, h, kt) do { \
    const bf16_t* _s = Bbase + (long)((h) * 128 + srow) * ldb + (kt) * 64; \
    g2lds16(_s, &Bs[bb][(h) * 8192 + t * 8]); \
    g2lds16(_s + (long)64 * ldb, &Bs[bb][(h) * 8192 + 4096 + t * 8]); \
  } while (0)

  bf16x8 a[4][2], b[2][2];

#define LOADA(mh, bc) do { \
    _Pragma("unroll") \
    for (int fi2 = 0; fi2 < 4; ++fi2) { \
      const int row = (mh) * 128 + wr * 64 + fi2 * 16 + laneRow; \
      _Pragma("unroll") \
      for (int ks = 0; ks < 2; ++ks) { \
        const int off = ((bc) * 32768 + (row << 7) + (ks << 6) + laneK16) ^ rflip; \
        a[fi2][ks] = *reinterpret_cast<const bf16x8*>(AsB + off); \
      } \
    } \
  } while (0)
#define LOADB(nh, bc) do { \
    _Pragma("unroll") \
    for (int fj2 = 0; fj2 < 2; ++fj2) { \
      const int row = (nh) * 128 + wc * 32 + fj2 * 16 + laneRow; \
      _Pragma("unroll") \
      for (int ks = 0; ks < 2; ++ks) { \
        const int off = ((bc) * 32768 + (row << 7) + (ks << 6) + laneK16) ^ rflip; \
        b[fj2][ks] = *reinterpret_cast<const bf16x8*>(BsB + off); \
      } \
    } \
  } while (0)
#define QUAD(mh, nh) do { \
    _Pragma("unroll") \
    for (int fi2 = 0; fi2 < 4; ++fi2) \
      _Pragma("unroll") \
      for (int ks = 0; ks < 2; ++ks) \
        _Pragma("unroll") \
        for (int fj2 = 0; fj2 < 2; ++fj2) \
          acc[(mh) * 4 + fi2][(nh) * 2 + fj2] = __builtin_amdgcn_mfma_f32_16x16x32_bf16( \
              a[fi2][ks], b[fj2][ks], acc[(mh) * 4 + fi2][(nh) * 2 + fj2], 0, 0, 0); \
  } while (0)
#define PH_MID() do { \
    __builtin_amdgcn_s_barrier(); \
    asm volatile("s_waitcnt lgkmcnt(0)" ::: "memory"); \
    __builtin_amdgcn_sched_barrier(0); \
    __builtin_amdgcn_s_setprio(1); \
  } while (0)
#define PH_END() do { \
    __builtin_amdgcn_s_setprio(0); \
    __builtin_amdgcn_s_barrier(); \
  } while (0)
#define PH_ENDV() do { \
    __builtin_amdgcn_s_setprio(0); \
    asm volatile("s_waitcnt vmcnt(4)" ::: "memory"); \
    __builtin_amdgcn_s_barrier(); \
  } while (0)

  const int NT = K >> 6;
  const int NITER = K >> 7;

  STAGE_A(0, 0, 0);
  STAGE_B(0, 0, 0);
  STAGE_A(0, 1, 0);
  STAGE_B(0, 1, 0);
  STAGE_A(1, 0, 1);
  STAGE_B(1, 0, 1);
  asm volatile("s_waitcnt vmcnt(4)" ::: "memory");
  __builtin_amdgcn_s_barrier();

  for (int it = 0; it < NITER; ++it) {
    const int T1 = 2 * it + 1;
    int T2 = 2 * it + 2; if (T2 >= NT) T2 = NT - 1;   // clamped prefetch (garbage,
    int T3 = 2 * it + 3; if (T3 >= NT) T3 = NT - 1;   // never computed) keeps vmcnt exact
    LOADA(0, 0); LOADB(0, 0);
    STAGE_A(1, 1, T1);
    PH_MID(); QUAD(0, 0); PH_END();
    LOADB(1, 0);
    STAGE_B(1, 1, T1);
    PH_MID(); QUAD(0, 1); PH_END();
    LOADA(1, 0); LOADB(0, 0);
    STAGE_A(0, 0, T2);
    PH_MID(); QUAD(1, 0); PH_END();
    LOADB(1, 0);
    STAGE_B(0, 0, T2);
    PH_MID(); QUAD(1, 1); PH_ENDV();
    LOADA(0, 1); LOADB(0, 1);
    STAGE_A(0, 1, T2);
    PH_MID(); QUAD(0, 0); PH_END();
    LOADB(1, 1);
    STAGE_B(0, 1, T2);
    PH_MID(); QUAD(0, 1); PH_END();
    LOADA(1, 1); LOADB(0, 1);
    STAGE_A(1, 0, T3);
    PH_MID(); QUAD(1, 0); PH_END();
    LOADB(1, 1);
    STAGE_B(1, 0, T3);
    PH_MID(); QUAD(1, 1); PH_ENDV();
  }

  const int er = (lane >> 4) << 2;
  const int ec = lane & 15;
  #pragma unroll
  for (int mh = 0; mh < 2; ++mh)
  #pragma unroll
  for (int fi2 = 0; fi2 < 4; ++fi2) {
    const int mg = m0 + mh * 128 + wr * 64 + fi2 * 16 + er;
    #pragma unroll
    for (int nh = 0; nh < 2; ++nh)
    #pragma unroll
    for (int fj2 = 0; fj2 < 2; ++fj2) {
      const int ng = n0 + nh * 128 + wc * 32 + fj2 * 16 + ec;
      const f32x4 v = acc[mh * 4 + fi2][nh * 2 + fj2];
      bf16_t* os = o_s + (long)bz * sOz;
      #pragma unroll
      for (int r = 0; r < 4; ++r)
        os[(long)(mg + r) * ldo + ng] = (bf16_t)(v[r] * scale);
    }
  }
#undef STAGE_A
#undef STAGE_B
#undef LOADA
#undef LOADB
#undef QUAD
#undef PH_MID
#undef PH_END
#undef PH_ENDV
}

// ---------------------------------------------------------------------------
// 128(M)x256(N) BT-GEMM, BK=64, 3 LDS buffers (144 KiB), 2 phases/tile,
// stage T+2 during T, vmcnt(6) once per tile (R4-validated schedule).
// MODE 0: QKV epilogue (bias; Q,K row-major bf16; V transposed to Vt)
// MODE 2: f32 out (PV)
// ---------------------------------------------------------------------------
template<int MODE>
__global__ __launch_bounds__(512, 2) void gemm128(
    const bf16_t* __restrict__ A, const bf16_t* __restrict__ B,
    int lda, int ldb, int K, int ldo,
    long sAz, long sBz, long sOz,
    bf16_t* __restrict__ o_q, bf16_t* __restrict__ o_k, bf16_t* __restrict__ o_vt,
    const float* __restrict__ bqp, const float* __restrict__ bkp, const float* __restrict__ bvp,
    float* __restrict__ o_f)
{
  __shared__ bf16_t As3[3][8192];    // [buf][128 rows x 64 cols]
  __shared__ bf16_t Bs3[3][16384];   // [buf][256 rows x 64 cols]
  const int t = threadIdx.x;
  const int lane = t & 63;
  const int wave = t >> 6;
  const int wr = wave >> 2, wc = wave & 3;
  const int m0 = blockIdx.y * 128, n0 = blockIdx.x * 256;
  const int bz = blockIdx.z;
  A += (long)bz * sAz;
  B += (long)bz * sBz;

  const int srow = t >> 3;                                    // 0..63
  const int scolB = (((t & 7) << 4) ^ ((srow & 7) << 4));     // byte col 0..127
  const bf16_t* Abase = A + (long)m0 * lda + (scolB >> 1);
  const bf16_t* Bbase = B + (long)n0 * ldb + (scolB >> 1);

  const int laneRow = lane & 15;
  const int laneK16 = (lane >> 4) << 4;
  const int rflip = (laneRow & 7) << 4;
  const char* AsB = (const char*)&As3[0][0];
  const char* BsB = (const char*)&Bs3[0][0];

  f32x4 acc[4][4];
  #pragma unroll
  for (int i = 0; i < 4; ++i)
    #pragma unroll
    for (int j = 0; j < 4; ++j) { f32x4 z = {0.f, 0.f, 0.f, 0.f}; acc[i][j] = z; }

#define PSTAGE_A(se, kt) do { \
    const bf16_t* _s = Abase + (long)srow * lda + (kt) * 64; \
    g2lds16(_s, &As3[0][0] + (se) + t * 8); \
    g2lds16(_s + (long)64 * lda, &As3[0][0] + (se) + 4096 + t * 8); \
  } while (0)
#define PSTAGE_B(se, h, kt) do { \
    const bf16_t* _s = Bbase + (long)((h) * 128 + srow) * ldb + (kt) * 64; \
    g2lds16(_s, &Bs3[0][0] + (se) + (h) * 8192 + t * 8); \
    g2lds16(_s + (long)64 * ldb, &Bs3[0][0] + (se) + (h) * 8192 + 4096 + t * 8); \
  } while (0)

  bf16x8 a[4][2], b[2][2];

#define PLOADA(cAb) do { \
    _Pragma("unroll") \
    for (int fi2 = 0; fi2 < 4; ++fi2) { \
      const int row = wr * 64 + fi2 * 16 + laneRow; \
      _Pragma("unroll") \
      for (int ks = 0; ks < 2; ++ks) { \
        const int off = (cAb) + (((row << 7) + (ks << 6) + laneK16) ^ rflip); \
        a[fi2][ks] = *reinterpret_cast<const bf16x8*>(AsB + off); \
      } \
    } \
  } while (0)
#define PLOADB(nh, cBb) do { \
    _Pragma("unroll") \
    for (int fj2 = 0; fj2 < 2; ++fj2) { \
      const int row = (nh) * 128 + wc * 32 + fj2 * 16 + laneRow; \
      _Pragma("unroll") \
      for (int ks = 0; ks < 2; ++ks) { \
        const int off = (cBb) + (((row << 7) + (ks << 6) + laneK16) ^ rflip); \
        b[fj2][ks] = *reinterpret_cast<const bf16x8*>(BsB + off); \
      } \
    } \
  } while (0)
#define PQUAD(nh) do { \
    _Pragma("unroll") \
    for (int fi2 = 0; fi2 < 4; ++fi2) \
      _Pragma("unroll") \
      for (int ks = 0; ks < 2; ++ks) \
        _Pragma("unroll") \
        for (int fj2 = 0; fj2 < 2; ++fj2) \
          acc[fi2][(nh) * 2 + fj2] = __builtin_amdgcn_mfma_f32_16x16x32_bf16( \
              a[fi2][ks], b[fj2][ks], acc[fi2][(nh) * 2 + fj2], 0, 0, 0); \
  } while (0)
#define PPH_MID() do { \
    __builtin_amdgcn_s_barrier(); \
    asm volatile("s_waitcnt lgkmcnt(0)" ::: "memory"); \
    __builtin_amdgcn_sched_barrier(0); \
    __builtin_amdgcn_s_setprio(1); \
  } while (0)

  const int NT = K >> 6;

  // prologue: T0 -> slot0, T1 -> slot1 (12 loads); retire T0 (first 6)
  PSTAGE_A(0, 0);      PSTAGE_B(0, 0, 0);      PSTAGE_B(0, 1, 0);
  PSTAGE_A(8192, 1);   PSTAGE_B(16384, 0, 1);  PSTAGE_B(16384, 1, 1);
  asm volatile("s_waitcnt vmcnt(6)" ::: "memory");
  __builtin_amdgcn_s_barrier();

  int cAb = 0, cBb = 0;              // current buf byte offsets (A:16KB, B:32KB strides)
  int sAe = 16384, sBe = 32768;      // stage slot element offsets (slot (T+2)%3)

  for (int T = 0; T < NT; ++T) {
    int Tp2 = T + 2; if (Tp2 >= NT) Tp2 = NT - 1;   // clamped tail keeps vmcnt exact
    // p0: nh=0; stage T+2.A + T+2.B0
    PLOADA(cAb); PLOADB(0, cBb);
    PSTAGE_A(sAe, Tp2);
    PSTAGE_B(sBe, 0, Tp2);
    PPH_MID(); PQUAD(0);
    __builtin_amdgcn_s_setprio(0);
    __builtin_amdgcn_s_barrier();
    // p1: nh=1; stage T+2.B1; counted wait -> T+1 fully landed
    PLOADB(1, cBb);
    PSTAGE_B(sBe, 1, Tp2);
    PPH_MID(); PQUAD(1);
    __builtin_amdgcn_s_setprio(0);
    asm volatile("s_waitcnt vmcnt(6)" ::: "memory");
    __builtin_amdgcn_s_barrier();
    cAb = (cAb == 32768) ? 0 : cAb + 16384;
    cBb = (cBb == 65536) ? 0 : cBb + 32768;
    sAe = (sAe == 16384) ? 0 : sAe + 8192;
    sBe = (sBe == 32768) ? 0 : sBe + 16384;
  }

  // epilogue: C/D frag layout col=lane&15, row=(lane>>4)*4+r
  const int er = (lane >> 4) << 2;
  const int ec = lane & 15;
  #pragma unroll
  for (int fi2 = 0; fi2 < 4; ++fi2) {
    const int mg = m0 + wr * 64 + fi2 * 16 + er;
    #pragma unroll
    for (int nh = 0; nh < 2; ++nh)
    #pragma unroll
    for (int fj2 = 0; fj2 < 2; ++fj2) {
      const int ng = n0 + nh * 128 + wc * 32 + fj2 * 16 + ec;
      const f32x4 v = acc[fi2][nh * 2 + fj2];
      if constexpr (MODE == 0) {
        if (ng < 1024) {
          const float bb = bqp[ng];
          #pragma unroll
          for (int r = 0; r < 4; ++r)
            o_q[(long)(mg + r) * 1024 + ng] = (bf16_t)(v[r] + bb);
        } else if (ng < 2048) {
          const int nn = ng - 1024;
          const float bb = bkp[nn];
          #pragma unroll
          for (int r = 0; r < 4; ++r)
            o_k[(long)(mg + r) * 1024 + nn] = (bf16_t)(v[r] + bb);
        } else {
          const int nn = ng - 2048;
          const float bb = bvp[nn];
          const int bat = mg >> 11, sr = mg & 2047;
          union { bf16_t h[4]; uint2 u; } pk;
          #pragma unroll
          for (int r = 0; r < 4; ++r) pk.h[r] = (bf16_t)(v[r] + bb);
          *reinterpret_cast<uint2*>(&o_vt[((long)bat * 1024 + nn) * 2048 + sr]) = pk.u;
        }
      } else {
        float* of = o_f + (long)bz * sOz;
        #pragma unroll
        for (int r = 0; r < 4; ++r)
          of[(long)(mg + r) * ldo + ng] = v[r];
      }
    }
  }
#undef PSTAGE_A
#undef PSTAGE_B
#undef PLOADA
#undef PLOADB
#undef PQUAD
#undef PPH_MID
}

extern "C" void kernel_launch(void* const* d_in, const int* in_sizes, int n_in,
                              void* d_out, int out_size, void* d_ws, size_t ws_size,
                              hipStream_t stream) {
  const float* X  = (const float*)d_in[0];
  const float* Wq = (const float*)d_in[1];
  const float* bq = (const float*)d_in[2];
  const float* Wk = (const float*)d_in[3];
  const float* bk = (const float*)d_in[4];
  const float* Wv = (const float*)d_in[5];
  const float* bv = (const float*)d_in[6];
  float* out = (float*)d_out;

  // ws layout (80 MiB):
  // [0:16M) Q bf16 [8192,1024] | [16:32M) K bf16 | [32:48M) Vt bf16 [4,1024,2048]
  // [48:64M) Xb bf16 | [64:70M) Wc bf16 [3072,1024] | [48:80M) P bf16 [4,2048,2048]
  constexpr long SEG = 16777216;
  char* ws = (char*)d_ws;
  bf16_t* Q  = (bf16_t*)(ws + 0 * SEG);
  bf16_t* Kc = (bf16_t*)(ws + 1 * SEG);
  bf16_t* Vt = (bf16_t*)(ws + 2 * SEG);
  bf16_t* Xb = (bf16_t*)(ws + 3 * SEG);
  bf16_t* Wc = (bf16_t*)(ws + 4 * SEG);
  bf16_t* P  = (bf16_t*)(ws + 3 * SEG);

  // fused casts: 1441792 groups of 8 = 5632 blocks
  cast_all<<<5632, 256, 0, stream>>>(X, Wq, Wk, Wv, Xb, Wc);

  dim3 blk(512);
  {  // QKV: M=8192, N=3072, K=1024 — 128x256 tiles, 768 blocks = 3 exact rounds
    dim3 g(3072 / 256, 8192 / 128, 1);
    gemm128<0><<<g, blk, 0, stream>>>(Xb, Wc, 1024, 1024, 1024, 1024, 0, 0, 0,
                                      Q, Kc, Vt, bq, bk, bv, nullptr);
  }
  {  // scores: per batch M=N=2048, K=1024; P = (Q K^T)/32 in bf16  (256 blocks)
    dim3 g(2048 / 256, 2048 / 256, 4);
    gemm8p<1><<<g, blk, 0, stream>>>(Q, Kc, 1024, 1024, 1024, 2048,
                                     2097152, 2097152, 4194304,
                                     P, 0.03125f);
  }
  softmax_rows<<<8192, 256, 0, stream>>>(P);
  {  // PV: per batch M=2048, N=1024, K=2048 -> f32 out  (256 blocks)
    dim3 g(1024 / 256, 2048 / 128, 4);
    gemm128<2><<<g, blk, 0, stream>>>(P, Vt, 2048, 2048, 2048, 1024,
                                      4194304, 2097152, 2097152,
                                      nullptr, nullptr, nullptr, nullptr, nullptr, nullptr,
                                      out);
  }
}